// Round 1
// baseline (279.185 us; speedup 1.0000x reference)
//
#include <hip/hip_runtime.h>
#include <math.h>

#define BB 16
#define SS 2048
#define DD 768

// 1/sqrt(768)
#define NORM_SCALE 0.036084391824351615f

// ---------------------------------------------------------------------------
// rowdot: dst[b*DD+e] = dot(src[b*src_stride : +DD], W[e*DD : +DD])
// one wave per output element; 4 waves per 256-thread block.
// grid = BB*DD/4 blocks.
// ---------------------------------------------------------------------------
__global__ void rowdot_kernel(const float* __restrict__ src, size_t src_stride,
                              const float* __restrict__ W,
                              float* __restrict__ dst) {
    int wid  = blockIdx.x * (blockDim.x >> 6) + (threadIdx.x >> 6);
    int lane = threadIdx.x & 63;
    int b = wid / DD;
    int e = wid % DD;
    const float* xr = src + (size_t)b * src_stride;
    const float* wr = W + (size_t)e * DD;
    float acc = 0.f;
#pragma unroll
    for (int i = 0; i < DD / 64; ++i) {
        int d = lane + i * 64;
        acc += xr[d] * wr[d];
    }
#pragma unroll
    for (int off = 32; off > 0; off >>= 1) acc += __shfl_down(acc, off);
    if (lane == 0) dst[b * DD + e] = acc;
}

// ---------------------------------------------------------------------------
// kq[b,d] = NORM * sum_e q0[b,e] * Wk[e*DD + d]   (i.e. q0 @ Wk, scaled)
// one block per b; 256 threads, each owns 3 columns d. Wk reads coalesced.
// ---------------------------------------------------------------------------
__global__ void kq_kernel(const float* __restrict__ q0,
                          const float* __restrict__ Wk,
                          float* __restrict__ kqs) {
    __shared__ float qrow[DD];
    int b = blockIdx.x;
    for (int i = threadIdx.x; i < DD; i += 256) qrow[i] = q0[b * DD + i];
    __syncthreads();
    int d0 = threadIdx.x, d1 = d0 + 256, d2 = d0 + 512;
    float a0 = 0.f, a1 = 0.f, a2 = 0.f;
#pragma unroll 4
    for (int e = 0; e < DD; ++e) {
        float q = qrow[e];
        const float* w = Wk + (size_t)e * DD;
        a0 += q * w[d0];
        a1 += q * w[d1];
        a2 += q * w[d2];
    }
    kqs[b * DD + d0] = a0 * NORM_SCALE;
    kqs[b * DD + d1] = a1 * NORM_SCALE;
    kqs[b * DD + d2] = a2 * NORM_SCALE;
}

// ---------------------------------------------------------------------------
// scores[b,s] = dot(b_in[b,s,:], kqs[b,:])  -- one wave per (b,s) row
// grid = BB*SS/4 blocks of 256.
// ---------------------------------------------------------------------------
__global__ void score_kernel(const float* __restrict__ x,
                             const float* __restrict__ kqs,
                             float* __restrict__ scores) {
    int wid  = blockIdx.x * (blockDim.x >> 6) + (threadIdx.x >> 6);
    int lane = threadIdx.x & 63;
    int b = wid / SS;
    int s = wid % SS;
    const float* xr = x + (size_t)(b * SS + s) * DD;
    const float* kr = kqs + b * DD;
    float acc = 0.f;
#pragma unroll
    for (int i = 0; i < DD / 64; ++i) {
        int d = lane + i * 64;
        acc += xr[d] * kr[d];
    }
#pragma unroll
    for (int off = 32; off > 0; off >>= 1) acc += __shfl_down(acc, off);
    if (lane == 0) scores[wid] = acc;
}

// ---------------------------------------------------------------------------
// softmax over SS per batch; also zero-inits c[b,:] for the atomics pass.
// one block (256 threads) per b; 8 scores per thread.
// ---------------------------------------------------------------------------
__global__ void softmax_kernel(const float* __restrict__ scores,
                               float* __restrict__ attn,
                               float* __restrict__ c) {
    __shared__ float redm[4];
    __shared__ float reds[4];
    __shared__ float bcast[2];
    int b = blockIdx.x;
    int tid = threadIdx.x;
    int wave = tid >> 6, lane = tid & 63;

    for (int d = tid; d < DD; d += 256) c[b * DD + d] = 0.f;

    float v[8];
    float mx = -INFINITY;
#pragma unroll
    for (int i = 0; i < 8; ++i) {
        v[i] = scores[b * SS + tid + i * 256];
        mx = fmaxf(mx, v[i]);
    }
#pragma unroll
    for (int off = 32; off > 0; off >>= 1) mx = fmaxf(mx, __shfl_down(mx, off));
    if (lane == 0) redm[wave] = mx;
    __syncthreads();
    if (tid == 0) {
        float m = fmaxf(fmaxf(redm[0], redm[1]), fmaxf(redm[2], redm[3]));
        bcast[0] = m;
    }
    __syncthreads();
    mx = bcast[0];

    float sum = 0.f;
#pragma unroll
    for (int i = 0; i < 8; ++i) {
        v[i] = expf(v[i] - mx);
        sum += v[i];
    }
#pragma unroll
    for (int off = 32; off > 0; off >>= 1) sum += __shfl_down(sum, off);
    if (lane == 0) reds[wave] = sum;
    __syncthreads();
    if (tid == 0) {
        bcast[1] = 1.f / (reds[0] + reds[1] + reds[2] + reds[3]);
    }
    __syncthreads();
    float inv = bcast[1];
#pragma unroll
    for (int i = 0; i < 8; ++i) attn[b * SS + tid + i * 256] = v[i] * inv;
}

// ---------------------------------------------------------------------------
// c[b,d] += sum_{s in chunk} attn[b,s] * b_in[b,s,d]
// grid (32 chunks, BB batches); 256 threads each owning 3 columns.
// ---------------------------------------------------------------------------
__global__ void cacc_kernel(const float* __restrict__ x,
                            const float* __restrict__ attn,
                            float* __restrict__ c) {
    int chunk = blockIdx.x;  // 0..31
    int b     = blockIdx.y;  // 0..15
    int tid   = threadIdx.x;
    int d0 = tid, d1 = tid + 256, d2 = tid + 512;
    const int ROWS = SS / 32;  // 64
    int s0 = chunk * ROWS;
    float a0 = 0.f, a1 = 0.f, a2 = 0.f;
#pragma unroll 4
    for (int r = 0; r < ROWS; ++r) {
        int s = s0 + r;
        float a = attn[b * SS + s];
        const float* xr = x + (size_t)(b * SS + s) * DD;
        a0 += a * xr[d0];
        a1 += a * xr[d1];
        a2 += a * xr[d2];
    }
    atomicAdd(&c[b * DD + d0], a0);
    atomicAdd(&c[b * DD + d1], a1);
    atomicAdd(&c[b * DD + d2], a2);
}

extern "C" void kernel_launch(void* const* d_in, const int* in_sizes, int n_in,
                              void* d_out, int out_size, void* d_ws, size_t ws_size,
                              hipStream_t stream) {
    const float* b_in = (const float*)d_in[0];
    // d_in[1] = mask: provably dead (masks whole query rows; only row 0 is
    // returned and row 0 is always unmasked) -- unused.
    const float* Wq = (const float*)d_in[2];
    const float* Wk = (const float*)d_in[3];
    const float* Wv = (const float*)d_in[4];
    float* out = (float*)d_out;

    float* ws     = (float*)d_ws;
    float* q0     = ws;                 // BB*DD
    float* kqs    = q0 + BB * DD;       // BB*DD
    float* scores = kqs + BB * DD;      // BB*SS
    float* attn   = scores + BB * SS;   // BB*SS
    float* c      = attn + BB * SS;     // BB*DD

    // 1) q0 = b_in[:,0,:] @ Wq^T
    rowdot_kernel<<<BB * DD / 4, 256, 0, stream>>>(b_in, (size_t)SS * DD, Wq, q0);
    // 2) kqs = (q0 @ Wk) * NORM
    kq_kernel<<<BB, 256, 0, stream>>>(q0, Wk, kqs);
    // 3) scores[b,s] = b_in[b,s,:] . kqs[b,:]
    score_kernel<<<BB * SS / 4, 256, 0, stream>>>(b_in, kqs, scores);
    // 4) softmax rows + zero c
    softmax_kernel<<<BB, 256, 0, stream>>>(scores, attn, c);
    // 5) c[b,:] = sum_s attn[b,s] * b_in[b,s,:]
    cacc_kernel<<<dim3(32, BB), 256, 0, stream>>>(b_in, attn, c);
    // 6) out = c @ Wv^T
    rowdot_kernel<<<BB * DD / 4, 256, 0, stream>>>(c, (size_t)DD, Wv, out);
}

// Round 2
// 195.446 us; speedup vs baseline: 1.4285x; 1.4285x over previous
//
#include <hip/hip_runtime.h>
#include <math.h>

#define BB 16
#define SS 2048
#define DD 768

// 1/sqrt(768); folded into q0 so kqs (and hence scores) come out pre-scaled.
#define NORM_SCALE 0.036084391824351615f

#define ECH 24           // e-chunks for split-K kq
#define EPC (DD / ECH)   // 32 e per chunk

// ---------------------------------------------------------------------------
// rowdot: dst[wid] = scale * dot(src[b*src_stride : +DD], W[e*DD : +DD])
// wid = b*DD + e. One wave per output element, float4 loads (3 per lane per
// operand). Optionally zero-fills zero_buf[wid] (used to init kqs before the
// atomic split-K pass, in stream order).
// ---------------------------------------------------------------------------
__global__ void rowdot_kernel(const float* __restrict__ src, size_t src_stride,
                              const float* __restrict__ W,
                              float* __restrict__ dst, float scale,
                              float* __restrict__ zero_buf) {
    int wid  = blockIdx.x * 4 + (threadIdx.x >> 6);
    int lane = threadIdx.x & 63;
    int b = wid / DD;
    int e = wid % DD;
    const float4* xr = (const float4*)(src + (size_t)b * src_stride);
    const float4* wr = (const float4*)(W + (size_t)e * DD);
    float acc = 0.f;
#pragma unroll
    for (int k = 0; k < 3; ++k) {
        float4 xv = xr[lane + k * 64];
        float4 wv = wr[lane + k * 64];
        acc += xv.x * wv.x + xv.y * wv.y + xv.z * wv.z + xv.w * wv.w;
    }
#pragma unroll
    for (int off = 32; off > 0; off >>= 1) acc += __shfl_down(acc, off);
    if (lane == 0) dst[wid] = acc * scale;
    if (zero_buf != nullptr && lane == 1) zero_buf[wid] = 0.f;
}

// ---------------------------------------------------------------------------
// Split-K kq: kqs[b,d] += sum_{e in chunk} q0[b,e] * Wk[e*DD + d]
// grid (ECH, BB), 192 threads; thread t owns float4 column t (192*4 = 768).
// Wk chunk rows are read fully coalesced (192 lanes * 16 B = 3 KB / iter).
// ---------------------------------------------------------------------------
__global__ void kq_split_kernel(const float* __restrict__ q0,
                                const float* __restrict__ Wk,
                                float* __restrict__ kqs) {
    __shared__ float qs[EPC];
    int echunk = blockIdx.x;
    int b      = blockIdx.y;
    int t      = threadIdx.x;  // 0..191
    if (t < EPC) qs[t] = q0[b * DD + echunk * EPC + t];
    __syncthreads();
    const float4* Wk4 = (const float4*)(Wk + (size_t)(echunk * EPC) * DD);
    float4 acc = {0.f, 0.f, 0.f, 0.f};
#pragma unroll 4
    for (int e = 0; e < EPC; ++e) {
        float q = qs[e];
        float4 w = Wk4[e * (DD / 4) + t];
        acc.x += q * w.x;
        acc.y += q * w.y;
        acc.z += q * w.z;
        acc.w += q * w.w;
    }
    float* dst = kqs + b * DD + t * 4;
    atomicAdd(dst + 0, acc.x);
    atomicAdd(dst + 1, acc.y);
    atomicAdd(dst + 2, acc.z);
    atomicAdd(dst + 3, acc.w);
}

// ---------------------------------------------------------------------------
// scores[b,s] = dot(b_in[b,s,:], kqs[b,:]) -- one wave per (b,s), float4.
// ---------------------------------------------------------------------------
__global__ void score_kernel(const float* __restrict__ x,
                             const float* __restrict__ kqs,
                             float* __restrict__ scores) {
    int wid  = blockIdx.x * 4 + (threadIdx.x >> 6);
    int lane = threadIdx.x & 63;
    int b = wid / SS;
    const float4* xr = (const float4*)(x + (size_t)wid * DD);
    const float4* kr = (const float4*)(kqs + b * DD);
    float acc = 0.f;
#pragma unroll
    for (int k = 0; k < 3; ++k) {
        float4 xv = xr[lane + k * 64];
        float4 kv = kr[lane + k * 64];
        acc += xv.x * kv.x + xv.y * kv.y + xv.z * kv.z + xv.w * kv.w;
    }
#pragma unroll
    for (int off = 32; off > 0; off >>= 1) acc += __shfl_down(acc, off);
    if (lane == 0) scores[wid] = acc;
}

// ---------------------------------------------------------------------------
// softmax over SS per batch; also zero-inits c[b,:] for the atomics pass.
// ---------------------------------------------------------------------------
__global__ void softmax_kernel(const float* __restrict__ scores,
                               float* __restrict__ attn,
                               float* __restrict__ c) {
    __shared__ float redm[4];
    __shared__ float reds[4];
    __shared__ float bcast[2];
    int b = blockIdx.x;
    int tid = threadIdx.x;
    int wave = tid >> 6, lane = tid & 63;

    for (int d = tid; d < DD; d += 256) c[b * DD + d] = 0.f;

    float v[8];
    float mx = -INFINITY;
#pragma unroll
    for (int i = 0; i < 8; ++i) {
        v[i] = scores[b * SS + tid + i * 256];
        mx = fmaxf(mx, v[i]);
    }
#pragma unroll
    for (int off = 32; off > 0; off >>= 1) mx = fmaxf(mx, __shfl_down(mx, off));
    if (lane == 0) redm[wave] = mx;
    __syncthreads();
    if (tid == 0) bcast[0] = fmaxf(fmaxf(redm[0], redm[1]), fmaxf(redm[2], redm[3]));
    __syncthreads();
    mx = bcast[0];

    float sum = 0.f;
#pragma unroll
    for (int i = 0; i < 8; ++i) {
        v[i] = expf(v[i] - mx);
        sum += v[i];
    }
#pragma unroll
    for (int off = 32; off > 0; off >>= 1) sum += __shfl_down(sum, off);
    if (lane == 0) reds[wave] = sum;
    __syncthreads();
    if (tid == 0) bcast[1] = 1.f / (reds[0] + reds[1] + reds[2] + reds[3]);
    __syncthreads();
    float inv = bcast[1];
#pragma unroll
    for (int i = 0; i < 8; ++i) attn[b * SS + tid + i * 256] = v[i] * inv;
}

// ---------------------------------------------------------------------------
// c[b,d] += sum_{s in chunk} attn[b,s] * b_in[b,s,d]
// grid (32, BB), 192 threads; thread t owns float4 column t. 64 rows/block.
// ---------------------------------------------------------------------------
__global__ void cacc_kernel(const float* __restrict__ x,
                            const float* __restrict__ attn,
                            float* __restrict__ c) {
    __shared__ float as[64];
    int chunk = blockIdx.x;  // 0..31
    int b     = blockIdx.y;  // 0..15
    int t     = threadIdx.x; // 0..191
    const int ROWS = SS / 32;  // 64
    int s0 = chunk * ROWS;
    if (t < ROWS) as[t] = attn[b * SS + s0 + t];
    __syncthreads();
    const float4* xb = (const float4*)(x + ((size_t)b * SS + s0) * DD);
    float4 acc = {0.f, 0.f, 0.f, 0.f};
#pragma unroll 4
    for (int r = 0; r < ROWS; ++r) {
        float a = as[r];
        float4 xv = xb[r * (DD / 4) + t];
        acc.x += a * xv.x;
        acc.y += a * xv.y;
        acc.z += a * xv.z;
        acc.w += a * xv.w;
    }
    float* dst = c + b * DD + t * 4;
    atomicAdd(dst + 0, acc.x);
    atomicAdd(dst + 1, acc.y);
    atomicAdd(dst + 2, acc.z);
    atomicAdd(dst + 3, acc.w);
}

extern "C" void kernel_launch(void* const* d_in, const int* in_sizes, int n_in,
                              void* d_out, int out_size, void* d_ws, size_t ws_size,
                              hipStream_t stream) {
    const float* b_in = (const float*)d_in[0];
    // d_in[1] = mask: provably dead (masks whole query rows; only query row 0
    // is returned and row 0 is always unmasked) -- unused.
    const float* Wq = (const float*)d_in[2];
    const float* Wk = (const float*)d_in[3];
    const float* Wv = (const float*)d_in[4];
    float* out = (float*)d_out;

    float* ws     = (float*)d_ws;
    float* q0     = ws;                 // BB*DD
    float* kqs    = q0 + BB * DD;       // BB*DD
    float* scores = kqs + BB * DD;      // BB*SS
    float* attn   = scores + BB * SS;   // BB*SS
    float* c      = attn + BB * SS;     // BB*DD

    // 1) q0 = NORM * (b_in[:,0,:] @ Wq^T); also zero-init kqs (stream-ordered
    //    before the atomic split-K pass). 12288 waves == BB*DD elements.
    rowdot_kernel<<<BB * DD / 4, 256, 0, stream>>>(b_in, (size_t)SS * DD, Wq,
                                                   q0, NORM_SCALE, kqs);
    // 2) kqs += q0 @ Wk (split-K over 24 e-chunks, 384 blocks)
    kq_split_kernel<<<dim3(ECH, BB), 192, 0, stream>>>(q0, Wk, kqs);
    // 3) scores[b,s] = b_in[b,s,:] . kqs[b,:]
    score_kernel<<<BB * SS / 4, 256, 0, stream>>>(b_in, kqs, scores);
    // 4) softmax rows + zero c
    softmax_kernel<<<BB, 256, 0, stream>>>(scores, attn, c);
    // 5) c[b,:] = sum_s attn[b,s] * b_in[b,s,:]
    cacc_kernel<<<dim3(32, BB), 192, 0, stream>>>(b_in, attn, c);
    // 6) out = c @ Wv^T
    rowdot_kernel<<<BB * DD / 4, 256, 0, stream>>>(c, (size_t)DD, Wv, out,
                                                   1.f, nullptr);
}

// Round 3
// 191.300 us; speedup vs baseline: 1.4594x; 1.0217x over previous
//
#include <hip/hip_runtime.h>
#include <math.h>

#define BB 16
#define SS 2048
#define DD 768

// 1/sqrt(768); folded into q0 so kqs (and hence scores) come out pre-scaled.
#define NORM_SCALE 0.036084391824351615f

#define ECH 24           // e-chunks for split-K kq
#define EPC (DD / ECH)   // 32 e per chunk

#define RPC 16           // rows per flash chunk
#define NCH (SS / RPC)   // 128 chunks per batch

// ---------------------------------------------------------------------------
// rowdot: dst[wid] = scale * dot(src[b*src_stride : +DD], W[e*DD : +DD])
// wid = b*DD + e. One wave per output element, float4 loads. Optionally
// zero-fills zero_buf[wid] (inits kqs before the atomic split-K pass).
// ---------------------------------------------------------------------------
__global__ void rowdot_kernel(const float* __restrict__ src, size_t src_stride,
                              const float* __restrict__ W,
                              float* __restrict__ dst, float scale,
                              float* __restrict__ zero_buf) {
    int wid  = blockIdx.x * 4 + (threadIdx.x >> 6);
    int lane = threadIdx.x & 63;
    int b = wid / DD;
    int e = wid % DD;
    const float4* xr = (const float4*)(src + (size_t)b * src_stride);
    const float4* wr = (const float4*)(W + (size_t)e * DD);
    float acc = 0.f;
#pragma unroll
    for (int k = 0; k < 3; ++k) {
        float4 xv = xr[lane + k * 64];
        float4 wv = wr[lane + k * 64];
        acc += xv.x * wv.x + xv.y * wv.y + xv.z * wv.z + xv.w * wv.w;
    }
#pragma unroll
    for (int off = 32; off > 0; off >>= 1) acc += __shfl_down(acc, off);
    if (lane == 0) dst[wid] = acc * scale;
    if (zero_buf != nullptr && lane == 1) zero_buf[wid] = 0.f;
}

// ---------------------------------------------------------------------------
// Split-K kq: kqs[b,d] += sum_{e in chunk} q0[b,e] * Wk[e*DD + d]
// grid (ECH, BB), 192 threads; thread t owns float4 column t.
// ---------------------------------------------------------------------------
__global__ void kq_split_kernel(const float* __restrict__ q0,
                                const float* __restrict__ Wk,
                                float* __restrict__ kqs) {
    __shared__ float qs[EPC];
    int echunk = blockIdx.x;
    int b      = blockIdx.y;
    int t      = threadIdx.x;  // 0..191
    if (t < EPC) qs[t] = q0[b * DD + echunk * EPC + t];
    __syncthreads();
    const float4* Wk4 = (const float4*)(Wk + (size_t)(echunk * EPC) * DD);
    float4 acc = {0.f, 0.f, 0.f, 0.f};
#pragma unroll 4
    for (int e = 0; e < EPC; ++e) {
        float q = qs[e];
        float4 w = Wk4[e * (DD / 4) + t];
        acc.x += q * w.x;
        acc.y += q * w.y;
        acc.z += q * w.z;
        acc.w += q * w.w;
    }
    float* dst = kqs + b * DD + t * 4;
    atomicAdd(dst + 0, acc.x);
    atomicAdd(dst + 1, acc.y);
    atomicAdd(dst + 2, acc.z);
    atomicAdd(dst + 3, acc.w);
}

// ---------------------------------------------------------------------------
// Flash pass (the ONLY full read of b_in):
// per (chunk, b) block: 16 rows. Step A streams rows to LDS while computing
// scores[r] = row . kqs (kqs fragment held in registers per lane). Step B
// forms unnormalized chunk partials with chunk-local max:
//   m_c = max_r sc[r]; p_r = exp(sc[r]-m_c); l_c = sum p_r;
//   o_c[d] = sum_r p_r * x[r][d]  (rows re-read from LDS, not HBM)
// grid (NCH, BB), 256 threads (4 waves x 4 rows each).
// ---------------------------------------------------------------------------
__global__ void flash_kernel(const float* __restrict__ x,
                             const float* __restrict__ kqs,
                             float* __restrict__ m_part,
                             float* __restrict__ l_part,
                             float* __restrict__ o_part) {
    __shared__ float xs[RPC * DD];   // 48 KB row stage
    __shared__ float sc[RPC];
    __shared__ float p[RPC];
    __shared__ float mbc[1];
    int chunk = blockIdx.x;   // 0..NCH-1
    int b     = blockIdx.y;   // 0..BB-1
    int tid   = threadIdx.x;
    int wave  = tid >> 6, lane = tid & 63;
    int s0    = chunk * RPC;

    // per-lane kqs fragment (12 floats), identical for every row
    const float4* kr = (const float4*)(kqs + b * DD);
    float4 kf0 = kr[lane];
    float4 kf1 = kr[lane + 64];
    float4 kf2 = kr[lane + 128];

#pragma unroll
    for (int j = 0; j < 4; ++j) {
        int r = wave * 4 + j;
        const float4* xr = (const float4*)(x + ((size_t)b * SS + s0 + r) * DD);
        float4 x0 = xr[lane];
        float4 x1 = xr[lane + 64];
        float4 x2 = xr[lane + 128];
        float4* xsr = (float4*)(xs + r * DD);
        xsr[lane]       = x0;
        xsr[lane + 64]  = x1;
        xsr[lane + 128] = x2;
        float acc = x0.x * kf0.x + x0.y * kf0.y + x0.z * kf0.z + x0.w * kf0.w
                  + x1.x * kf1.x + x1.y * kf1.y + x1.z * kf1.z + x1.w * kf1.w
                  + x2.x * kf2.x + x2.y * kf2.y + x2.z * kf2.z + x2.w * kf2.w;
#pragma unroll
        for (int off = 32; off > 0; off >>= 1) acc += __shfl_down(acc, off);
        if (lane == 0) sc[r] = acc;
    }
    __syncthreads();

    if (tid == 0) {
        float m = sc[0];
#pragma unroll
        for (int r = 1; r < RPC; ++r) m = fmaxf(m, sc[r]);
        mbc[0] = m;
    }
    __syncthreads();
    if (tid < RPC) p[tid] = expf(sc[tid] - mbc[0]);
    __syncthreads();

    // Step B: thread owns columns tid, tid+256, tid+512
    float a0 = 0.f, a1 = 0.f, a2 = 0.f;
#pragma unroll
    for (int r = 0; r < RPC; ++r) {
        float pr = p[r];
        a0 += pr * xs[r * DD + tid];
        a1 += pr * xs[r * DD + tid + 256];
        a2 += pr * xs[r * DD + tid + 512];
    }
    int pidx = b * NCH + chunk;
    float* op = o_part + (size_t)pidx * DD;
    op[tid]       = a0;
    op[tid + 256] = a1;
    op[tid + 512] = a2;
    if (tid == 0) {
        float l = 0.f;
#pragma unroll
        for (int r = 0; r < RPC; ++r) l += p[r];
        m_part[pidx] = mbc[0];
        l_part[pidx] = l;
    }
}

// ---------------------------------------------------------------------------
// Combine: per batch, rescale chunk partials with global max and normalize:
//   M = max_c m_c; w_c = exp(m_c - M); l = sum w_c l_c
//   c[b,d] = (sum_c w_c o_c[d]) / l
// grid BB, 256 threads.
// ---------------------------------------------------------------------------
__global__ void combine_kernel(const float* __restrict__ m_part,
                               const float* __restrict__ l_part,
                               const float* __restrict__ o_part,
                               float* __restrict__ c) {
    __shared__ float w[NCH];
    __shared__ float bc[2];  // M, 1/l
    int b = blockIdx.x;
    int tid = threadIdx.x;

    if (tid < NCH) w[tid] = m_part[b * NCH + tid];
    __syncthreads();
    if (tid == 0) {
        float M = w[0];
        for (int i = 1; i < NCH; ++i) M = fmaxf(M, w[i]);
        bc[0] = M;
    }
    __syncthreads();
    float M = bc[0];
    if (tid < NCH) w[tid] = expf(w[tid] - M);
    __syncthreads();
    if (tid == 0) {
        float l = 0.f;
        for (int i = 0; i < NCH; ++i) l += w[i] * l_part[b * NCH + i];
        bc[1] = 1.f / l;
    }
    __syncthreads();
    float inv = bc[1];

    float a0 = 0.f, a1 = 0.f, a2 = 0.f;
    const float* op = o_part + (size_t)b * NCH * DD;
#pragma unroll 4
    for (int cc = 0; cc < NCH; ++cc) {
        float wc = w[cc];
        const float* o = op + (size_t)cc * DD;
        a0 += wc * o[tid];
        a1 += wc * o[tid + 256];
        a2 += wc * o[tid + 512];
    }
    c[b * DD + tid]       = a0 * inv;
    c[b * DD + tid + 256] = a1 * inv;
    c[b * DD + tid + 512] = a2 * inv;
}

extern "C" void kernel_launch(void* const* d_in, const int* in_sizes, int n_in,
                              void* d_out, int out_size, void* d_ws, size_t ws_size,
                              hipStream_t stream) {
    const float* b_in = (const float*)d_in[0];
    // d_in[1] = mask: provably dead (masks whole query rows; only query row 0
    // is returned and row 0 is always unmasked) -- unused.
    const float* Wq = (const float*)d_in[2];
    const float* Wk = (const float*)d_in[3];
    const float* Wv = (const float*)d_in[4];
    float* out = (float*)d_out;

    float* ws     = (float*)d_ws;
    float* q0     = ws;                        // BB*DD
    float* kqs    = q0 + BB * DD;              // BB*DD
    float* m_part = kqs + BB * DD;             // BB*NCH
    float* l_part = m_part + BB * NCH;         // BB*NCH
    float* o_part = l_part + BB * NCH;         // BB*NCH*DD (6.3 MB)
    float* c      = o_part + (size_t)BB * NCH * DD;  // BB*DD

    // 1) q0 = NORM * (b_in[:,0,:] @ Wq^T); zero-init kqs in stream order.
    rowdot_kernel<<<BB * DD / 4, 256, 0, stream>>>(b_in, (size_t)SS * DD, Wq,
                                                   q0, NORM_SCALE, kqs);
    // 2) kqs += q0 @ Wk (split-K over 24 e-chunks)
    kq_split_kernel<<<dim3(ECH, BB), 192, 0, stream>>>(q0, Wk, kqs);
    // 3) single pass over b_in: scores + chunk-local softmax + weighted sums
    flash_kernel<<<dim3(NCH, BB), 256, 0, stream>>>(b_in, kqs,
                                                    m_part, l_part, o_part);
    // 4) combine chunk partials -> c[b,:]
    combine_kernel<<<BB, 256, 0, stream>>>(m_part, l_part, o_part, c);
    // 5) out = c @ Wv^T
    rowdot_kernel<<<BB * DD / 4, 256, 0, stream>>>(c, (size_t)DD, Wv, out,
                                                   1.f, nullptr);
}

// Round 4
// 185.470 us; speedup vs baseline: 1.5053x; 1.0314x over previous
//
#include <hip/hip_runtime.h>
#include <math.h>

#define BB 16
#define SS 2048
#define DD 768

// 1/sqrt(768); folded into q0 so kqs (and hence scores) come out pre-scaled.
#define NORM_SCALE 0.036084391824351615f

#define ECH 24           // e-chunks for split-K kq
#define EPC (DD / ECH)   // 32 e per chunk

#define RPC 16           // rows per flash chunk
#define NCH (SS / RPC)   // 128 chunks per batch

// ---------------------------------------------------------------------------
// rowdot: dst[wid] = scale * dot(src[b*src_stride : +DD], W[e*DD : +DD])
// wid = b*DD + e. One wave per output element, float4 loads. Optionally
// zero-fills zero_buf[wid] (inits kqs before the atomic split-K pass).
// ---------------------------------------------------------------------------
__global__ void rowdot_kernel(const float* __restrict__ src, size_t src_stride,
                              const float* __restrict__ W,
                              float* __restrict__ dst, float scale,
                              float* __restrict__ zero_buf) {
    int wid  = blockIdx.x * 4 + (threadIdx.x >> 6);
    int lane = threadIdx.x & 63;
    int b = wid / DD;
    int e = wid % DD;
    const float4* xr = (const float4*)(src + (size_t)b * src_stride);
    const float4* wr = (const float4*)(W + (size_t)e * DD);
    float acc = 0.f;
#pragma unroll
    for (int k = 0; k < 3; ++k) {
        float4 xv = xr[lane + k * 64];
        float4 wv = wr[lane + k * 64];
        acc += xv.x * wv.x + xv.y * wv.y + xv.z * wv.z + xv.w * wv.w;
    }
#pragma unroll
    for (int off = 32; off > 0; off >>= 1) acc += __shfl_down(acc, off);
    if (lane == 0) dst[wid] = acc * scale;
    if (zero_buf != nullptr && lane == 1) zero_buf[wid] = 0.f;
}

// ---------------------------------------------------------------------------
// Split-K kq: kqs[b,d] += sum_{e in chunk} q0[b,e] * Wk[e*DD + d]
// grid (ECH, BB), 192 threads; thread t owns float4 column t.
// ---------------------------------------------------------------------------
__global__ void kq_split_kernel(const float* __restrict__ q0,
                                const float* __restrict__ Wk,
                                float* __restrict__ kqs) {
    __shared__ float qs[EPC];
    int echunk = blockIdx.x;
    int b      = blockIdx.y;
    int t      = threadIdx.x;  // 0..191
    if (t < EPC) qs[t] = q0[b * DD + echunk * EPC + t];
    __syncthreads();
    const float4* Wk4 = (const float4*)(Wk + (size_t)(echunk * EPC) * DD);
    float4 acc = {0.f, 0.f, 0.f, 0.f};
#pragma unroll 4
    for (int e = 0; e < EPC; ++e) {
        float q = qs[e];
        float4 w = Wk4[e * (DD / 4) + t];
        acc.x += q * w.x;
        acc.y += q * w.y;
        acc.z += q * w.z;
        acc.w += q * w.w;
    }
    float* dst = kqs + b * DD + t * 4;
    atomicAdd(dst + 0, acc.x);
    atomicAdd(dst + 1, acc.y);
    atomicAdd(dst + 2, acc.z);
    atomicAdd(dst + 3, acc.w);
}

// ---------------------------------------------------------------------------
// Flash pass (the ONLY full read of b_in), phase-separated for memory-level
// parallelism:
//   Phase 0: each wave fires 12 async global->LDS 16B loads back-to-back
//            (12 KB in flight per wave; no dependent stalls between issues).
//   Phase 1: (post-barrier) scores from LDS; chunk-local softmax.
//   Phase 2: unnormalized weighted row-sum from LDS -> o_part chunk partial.
// grid (NCH, BB), 256 threads (4 waves; wave w stages+dots rows 4w..4w+3).
// ---------------------------------------------------------------------------
__global__ void __launch_bounds__(256) flash_kernel(
        const float* __restrict__ x,
        const float* __restrict__ kqs,
        float* __restrict__ m_part,
        float* __restrict__ l_part,
        float* __restrict__ o_part) {
    __shared__ float xs[RPC * DD];   // 48 KB row stage, exact row-major layout
    __shared__ float sc[RPC];
    __shared__ float p[RPC];
    __shared__ float mbc[1];
    int chunk = blockIdx.x;   // 0..NCH-1
    int b     = blockIdx.y;   // 0..BB-1
    int tid   = threadIdx.x;
    int wave  = tid >> 6, lane = tid & 63;
    int s0    = chunk * RPC;

    // Phase 0: async stage 4 rows (12 KB) per wave. LDS dest is wave-uniform
    // base + lane*16 (global_load_lds constraint) -- layout is contiguous
    // row-major, matching xs exactly.
    const float* xg = x + ((size_t)b * SS + s0 + wave * 4) * DD;
    float*       xl = xs + wave * 4 * DD;
#pragma unroll
    for (int k = 0; k < 12; ++k) {
        __builtin_amdgcn_global_load_lds(
            (const __attribute__((address_space(1))) unsigned int*)(xg + k * 256 + lane * 4),
            (__attribute__((address_space(3))) unsigned int*)(xl + k * 256),
            16, 0, 0);
    }

    // kq fragment into registers while the async loads fly
    const float4* kr = (const float4*)(kqs + b * DD);
    float4 kf0 = kr[lane];
    float4 kf1 = kr[lane + 64];
    float4 kf2 = kr[lane + 128];

    __syncthreads();  // drains vmcnt (global_load_lds) + makes xs visible

    // Phase 1: dots from LDS (no global latency in this phase)
#pragma unroll
    for (int j = 0; j < 4; ++j) {
        int r = wave * 4 + j;
        const float4* xsr = (const float4*)(xs + r * DD);
        float4 x0 = xsr[lane];
        float4 x1 = xsr[lane + 64];
        float4 x2 = xsr[lane + 128];
        float acc = x0.x * kf0.x + x0.y * kf0.y + x0.z * kf0.z + x0.w * kf0.w
                  + x1.x * kf1.x + x1.y * kf1.y + x1.z * kf1.z + x1.w * kf1.w
                  + x2.x * kf2.x + x2.y * kf2.y + x2.z * kf2.z + x2.w * kf2.w;
#pragma unroll
        for (int off = 32; off > 0; off >>= 1) acc += __shfl_down(acc, off);
        if (lane == 0) sc[r] = acc;
    }
    __syncthreads();

    if (tid == 0) {
        float m = sc[0];
#pragma unroll
        for (int r = 1; r < RPC; ++r) m = fmaxf(m, sc[r]);
        mbc[0] = m;
    }
    __syncthreads();
    if (tid < RPC) p[tid] = expf(sc[tid] - mbc[0]);
    __syncthreads();

    // Phase 2: thread owns columns tid, tid+256, tid+512 (2-way LDS bank
    // aliasing only -- free on gfx950)
    float a0 = 0.f, a1 = 0.f, a2 = 0.f;
#pragma unroll
    for (int r = 0; r < RPC; ++r) {
        float pr = p[r];
        a0 += pr * xs[r * DD + tid];
        a1 += pr * xs[r * DD + tid + 256];
        a2 += pr * xs[r * DD + tid + 512];
    }
    int pidx = b * NCH + chunk;
    float* op = o_part + (size_t)pidx * DD;
    op[tid]       = a0;
    op[tid + 256] = a1;
    op[tid + 512] = a2;
    if (tid == 0) {
        float l = 0.f;
#pragma unroll
        for (int r = 0; r < RPC; ++r) l += p[r];
        m_part[pidx] = mbc[0];
        l_part[pidx] = l;
    }
}

// ---------------------------------------------------------------------------
// Combine: per (batch, column-segment) block, rescale chunk partials with the
// global max and normalize:
//   M = max_c m_c; w_c = exp(m_c - M); l = sum w_c l_c
//   c[b,col] = (sum_c w_c o_c[col]) / l
// grid (BB, 3), 256 threads; thread owns one column. M/w/l recomputed
// redundantly per block (128 values -- cheap).
// ---------------------------------------------------------------------------
__global__ void combine_kernel(const float* __restrict__ m_part,
                               const float* __restrict__ l_part,
                               const float* __restrict__ o_part,
                               float* __restrict__ c) {
    __shared__ float w[NCH];
    __shared__ float bc[2];  // M, 1/l
    int b   = blockIdx.x;
    int seg = blockIdx.y;
    int tid = threadIdx.x;

    if (tid < NCH) w[tid] = m_part[b * NCH + tid];
    __syncthreads();
    if (tid == 0) {
        float M = w[0];
        for (int i = 1; i < NCH; ++i) M = fmaxf(M, w[i]);
        bc[0] = M;
    }
    __syncthreads();
    float M = bc[0];
    if (tid < NCH) w[tid] = expf(w[tid] - M);
    __syncthreads();
    if (tid == 0) {
        float l = 0.f;
        for (int i = 0; i < NCH; ++i) l += w[i] * l_part[b * NCH + i];
        bc[1] = 1.f / l;
    }
    __syncthreads();
    float inv = bc[1];

    int col = seg * 256 + tid;
    const float* op = o_part + (size_t)b * NCH * DD + col;
    float a = 0.f;
#pragma unroll 8
    for (int cc = 0; cc < NCH; ++cc) a += w[cc] * op[(size_t)cc * DD];
    c[b * DD + col] = a * inv;
}

extern "C" void kernel_launch(void* const* d_in, const int* in_sizes, int n_in,
                              void* d_out, int out_size, void* d_ws, size_t ws_size,
                              hipStream_t stream) {
    const float* b_in = (const float*)d_in[0];
    // d_in[1] = mask: provably dead (masks whole query rows; only query row 0
    // is returned and row 0 is always unmasked) -- unused.
    const float* Wq = (const float*)d_in[2];
    const float* Wk = (const float*)d_in[3];
    const float* Wv = (const float*)d_in[4];
    float* out = (float*)d_out;

    float* ws     = (float*)d_ws;
    float* q0     = ws;                        // BB*DD
    float* kqs    = q0 + BB * DD;              // BB*DD
    float* m_part = kqs + BB * DD;             // BB*NCH
    float* l_part = m_part + BB * NCH;         // BB*NCH
    float* o_part = l_part + BB * NCH;         // BB*NCH*DD (6.3 MB)
    float* c      = o_part + (size_t)BB * NCH * DD;  // BB*DD

    // 1) q0 = NORM * (b_in[:,0,:] @ Wq^T); zero-init kqs in stream order.
    rowdot_kernel<<<BB * DD / 4, 256, 0, stream>>>(b_in, (size_t)SS * DD, Wq,
                                                   q0, NORM_SCALE, kqs);
    // 2) kqs += q0 @ Wk (split-K over 24 e-chunks)
    kq_split_kernel<<<dim3(ECH, BB), 192, 0, stream>>>(q0, Wk, kqs);
    // 3) single pass over b_in: async-staged scores + chunk softmax + w-sums
    flash_kernel<<<dim3(NCH, BB), 256, 0, stream>>>(b_in, kqs,
                                                    m_part, l_part, o_part);
    // 4) combine chunk partials -> c[b,:]
    combine_kernel<<<dim3(BB, 3), 256, 0, stream>>>(m_part, l_part, o_part, c);
    // 5) out = c @ Wv^T
    rowdot_kernel<<<BB * DD / 4, 256, 0, stream>>>(c, (size_t)DD, Wv, out,
                                                   1.f, nullptr);
}

// Round 5
// 182.236 us; speedup vs baseline: 1.5320x; 1.0177x over previous
//
#include <hip/hip_runtime.h>
#include <math.h>

#define BB 16
#define SS 2048
#define DD 768

// 1/sqrt(768); folded into q0 so kqs (and hence scores) come out pre-scaled.
#define NORM_SCALE 0.036084391824351615f

#define ECH 24           // e-chunks for split-K kq
#define EPC (DD / ECH)   // 32 e per chunk

#define RPC 16           // rows per flash chunk
#define NCH (SS / RPC)   // 128 chunks per batch

// ---------------------------------------------------------------------------
// rowdot: dst[wid] = scale * dot(src[b*src_stride : +DD], W[e*DD : +DD])
// wid = b*DD + e. One wave per output element, float4 loads. Optionally
// zero-fills zero_buf[wid] (inits kqs before the atomic split-K pass).
// ---------------------------------------------------------------------------
__global__ void rowdot_kernel(const float* __restrict__ src, size_t src_stride,
                              const float* __restrict__ W,
                              float* __restrict__ dst, float scale,
                              float* __restrict__ zero_buf) {
    int wid  = blockIdx.x * 4 + (threadIdx.x >> 6);
    int lane = threadIdx.x & 63;
    int b = wid / DD;
    int e = wid % DD;
    const float4* xr = (const float4*)(src + (size_t)b * src_stride);
    const float4* wr = (const float4*)(W + (size_t)e * DD);
    float acc = 0.f;
#pragma unroll
    for (int k = 0; k < 3; ++k) {
        float4 xv = xr[lane + k * 64];
        float4 wv = wr[lane + k * 64];
        acc += xv.x * wv.x + xv.y * wv.y + xv.z * wv.z + xv.w * wv.w;
    }
#pragma unroll
    for (int off = 32; off > 0; off >>= 1) acc += __shfl_down(acc, off);
    if (lane == 0) dst[wid] = acc * scale;
    if (zero_buf != nullptr && lane == 1) zero_buf[wid] = 0.f;
}

// ---------------------------------------------------------------------------
// Split-K kq: kqs[b,d] += sum_{e in chunk} q0[b,e] * Wk[e*DD + d]
// grid (ECH, BB), 192 threads; thread t owns float4 column t.
// ---------------------------------------------------------------------------
__global__ void kq_split_kernel(const float* __restrict__ q0,
                                const float* __restrict__ Wk,
                                float* __restrict__ kqs) {
    __shared__ float qs[EPC];
    int echunk = blockIdx.x;
    int b      = blockIdx.y;
    int t      = threadIdx.x;  // 0..191
    if (t < EPC) qs[t] = q0[b * DD + echunk * EPC + t];
    __syncthreads();
    const float4* Wk4 = (const float4*)(Wk + (size_t)(echunk * EPC) * DD);
    float4 acc = {0.f, 0.f, 0.f, 0.f};
#pragma unroll 4
    for (int e = 0; e < EPC; ++e) {
        float q = qs[e];
        float4 w = Wk4[e * (DD / 4) + t];
        acc.x += q * w.x;
        acc.y += q * w.y;
        acc.z += q * w.z;
        acc.w += q * w.w;
    }
    float* dst = kqs + b * DD + t * 4;
    atomicAdd(dst + 0, acc.x);
    atomicAdd(dst + 1, acc.y);
    atomicAdd(dst + 2, acc.z);
    atomicAdd(dst + 3, acc.w);
}

// ---------------------------------------------------------------------------
// Flash pass (the ONLY full read of b_in), register-resident:
// wave w holds rows 4w..4w+3 in 12 float4 registers (loads issued
// back-to-back -> 12 KB in flight per wave), dots + softmax via shuffles,
// weighted row-sum in registers, one 12 KB LDS cross-wave reduce at the end.
// Emits unnormalized chunk partials (m_c, l_c, o_c[768]).
// grid (NCH, BB), 256 threads.
// ---------------------------------------------------------------------------
__global__ void __launch_bounds__(256) flash_kernel(
        const float* __restrict__ x,
        const float* __restrict__ kqs,
        float* __restrict__ m_part,
        float* __restrict__ l_part,
        float* __restrict__ o_part) {
    __shared__ float4 osh[4 * 192];  // 12 KB: per-wave o partials
    __shared__ float sc[RPC];
    __shared__ float wsum[4];
    int chunk = blockIdx.x;   // 0..NCH-1
    int b     = blockIdx.y;   // 0..BB-1
    int tid   = threadIdx.x;
    int wave  = tid >> 6, lane = tid & 63;
    int s0    = chunk * RPC;

    // 12 independent global loads (4 rows x 3 float4-segments per lane)
    const float4* xr = (const float4*)(x + ((size_t)b * SS + s0 + wave * 4) * DD);
    float4 xv[12];
#pragma unroll
    for (int j = 0; j < 4; ++j)
#pragma unroll
        for (int k = 0; k < 3; ++k)
            xv[j * 3 + k] = xr[j * (DD / 4) + k * 64 + lane];

    const float4* kr = (const float4*)(kqs + b * DD);
    float4 kf[3];
#pragma unroll
    for (int k = 0; k < 3; ++k) kf[k] = kr[k * 64 + lane];

    // scores for this wave's 4 rows
#pragma unroll
    for (int j = 0; j < 4; ++j) {
        float acc = 0.f;
#pragma unroll
        for (int k = 0; k < 3; ++k) {
            float4 xx = xv[j * 3 + k];
            acc += xx.x * kf[k].x + xx.y * kf[k].y
                 + xx.z * kf[k].z + xx.w * kf[k].w;
        }
#pragma unroll
        for (int off = 32; off > 0; off >>= 1) acc += __shfl_down(acc, off);
        if (lane == 0) sc[wave * 4 + j] = acc;
    }
    __syncthreads();

    // chunk max (LDS broadcast reads, computed redundantly by every thread)
    float m = sc[0];
#pragma unroll
    for (int r = 1; r < RPC; ++r) m = fmaxf(m, sc[r]);

    // p for this wave's 4 rows: lanes 0..3 compute, broadcast via shuffle
    float pl = (lane < 4) ? expf(sc[wave * 4 + lane] - m) : 0.f;
    float p0 = __shfl(pl, 0), p1 = __shfl(pl, 1);
    float p2 = __shfl(pl, 2), p3 = __shfl(pl, 3);
    if (lane == 0) wsum[wave] = p0 + p1 + p2 + p3;

    // weighted row-sum in registers (col group i = k*64+lane -> cols 4i..4i+3)
#pragma unroll
    for (int k = 0; k < 3; ++k) {
        float4 a;
        a.x = p0 * xv[k].x + p1 * xv[3 + k].x + p2 * xv[6 + k].x + p3 * xv[9 + k].x;
        a.y = p0 * xv[k].y + p1 * xv[3 + k].y + p2 * xv[6 + k].y + p3 * xv[9 + k].y;
        a.z = p0 * xv[k].z + p1 * xv[3 + k].z + p2 * xv[6 + k].z + p3 * xv[9 + k].z;
        a.w = p0 * xv[k].w + p1 * xv[3 + k].w + p2 * xv[6 + k].w + p3 * xv[9 + k].w;
        osh[wave * 192 + k * 64 + lane] = a;
    }
    __syncthreads();

    int pidx = b * NCH + chunk;
    if (tid < 192) {
        float4 s0v = osh[tid], s1 = osh[192 + tid];
        float4 s2 = osh[384 + tid], s3 = osh[576 + tid];
        float4 s;
        s.x = s0v.x + s1.x + s2.x + s3.x;
        s.y = s0v.y + s1.y + s2.y + s3.y;
        s.z = s0v.z + s1.z + s2.z + s3.z;
        s.w = s0v.w + s1.w + s2.w + s3.w;
        ((float4*)(o_part + (size_t)pidx * DD))[tid] = s;
    }
    if (tid == 0) {
        m_part[pidx] = m;
        l_part[pidx] = wsum[0] + wsum[1] + wsum[2] + wsum[3];
    }
}

// ---------------------------------------------------------------------------
// Combine: per (batch, column-segment) block:
//   M = max_c m_c; w_c = exp(m_c - M); l = sum w_c l_c
//   c[b,col] = (sum_c w_c o_c[col]) / l
// grid (BB, 3), 256 threads; wave-parallel M and l reductions.
// ---------------------------------------------------------------------------
__global__ void combine_kernel(const float* __restrict__ m_part,
                               const float* __restrict__ l_part,
                               const float* __restrict__ o_part,
                               float* __restrict__ c) {
    __shared__ float w[NCH];
    __shared__ float bc[2];  // M, 1/l
    int b   = blockIdx.x;
    int seg = blockIdx.y;
    int tid = threadIdx.x;

    if (tid < 64) {
        float m = fmaxf(m_part[b * NCH + tid], m_part[b * NCH + tid + 64]);
#pragma unroll
        for (int off = 32; off > 0; off >>= 1) m = fmaxf(m, __shfl_down(m, off));
        if (tid == 0) bc[0] = m;
    }
    __syncthreads();
    float M = bc[0];
    if (tid < NCH) w[tid] = expf(m_part[b * NCH + tid] - M);
    __syncthreads();
    if (tid < 64) {
        float s = w[tid] * l_part[b * NCH + tid]
                + w[tid + 64] * l_part[b * NCH + tid + 64];
#pragma unroll
        for (int off = 32; off > 0; off >>= 1) s += __shfl_down(s, off);
        if (tid == 0) bc[1] = 1.f / s;
    }
    __syncthreads();
    float inv = bc[1];

    int col = seg * 256 + tid;
    const float* op = o_part + (size_t)b * NCH * DD + col;
    float a = 0.f;
#pragma unroll 8
    for (int cc = 0; cc < NCH; ++cc) a += w[cc] * op[(size_t)cc * DD];
    c[b * DD + col] = a * inv;
}

extern "C" void kernel_launch(void* const* d_in, const int* in_sizes, int n_in,
                              void* d_out, int out_size, void* d_ws, size_t ws_size,
                              hipStream_t stream) {
    const float* b_in = (const float*)d_in[0];
    // d_in[1] = mask: provably dead (masks whole query rows; only query row 0
    // is returned and row 0 is always unmasked) -- unused.
    const float* Wq = (const float*)d_in[2];
    const float* Wk = (const float*)d_in[3];
    const float* Wv = (const float*)d_in[4];
    float* out = (float*)d_out;

    float* ws     = (float*)d_ws;
    float* q0     = ws;                        // BB*DD
    float* kqs    = q0 + BB * DD;              // BB*DD
    float* m_part = kqs + BB * DD;             // BB*NCH
    float* l_part = m_part + BB * NCH;         // BB*NCH
    float* o_part = l_part + BB * NCH;         // BB*NCH*DD (6.3 MB)
    float* c      = o_part + (size_t)BB * NCH * DD;  // BB*DD

    // 1) q0 = NORM * (b_in[:,0,:] @ Wq^T); zero-init kqs in stream order.
    rowdot_kernel<<<BB * DD / 4, 256, 0, stream>>>(b_in, (size_t)SS * DD, Wq,
                                                   q0, NORM_SCALE, kqs);
    // 2) kqs += q0 @ Wk (split-K over 24 e-chunks)
    kq_split_kernel<<<dim3(ECH, BB), 192, 0, stream>>>(q0, Wk, kqs);
    // 3) single pass over b_in: register-resident scores+softmax+weighted sums
    flash_kernel<<<dim3(NCH, BB), 256, 0, stream>>>(b_in, kqs,
                                                    m_part, l_part, o_part);
    // 4) combine chunk partials -> c[b,:]
    combine_kernel<<<dim3(BB, 3), 256, 0, stream>>>(m_part, l_part, o_part, c);
    // 5) out = c @ Wv^T
    rowdot_kernel<<<BB * DD / 4, 256, 0, stream>>>(c, (size_t)DD, Wv, out,
                                                   1.f, nullptr);
}